// Round 1
// baseline (291253.027 us; speedup 1.0000x reference)
//
#include <hip/hip_runtime.h>

#define NB 64      // batch
#define NS 512     // seq len
#define NZ 256     // z dim
#define NH 1024    // hidden (HID == L == 1024)
#define NWG 256
#define NT 256

// ws layout (float offsets)
#define OFF_OUT  0                       // outT [NH][NB]
#define OFF_H1   (OFF_OUT + NH*NB)       // h1T  [2][NH][NB]
#define OFF_H2   (OFF_H1 + 2*NH*NB)      // h2T  [2][NH][NB]
#define OFF_C1   (OFF_H2 + 2*NH*NB)      // c1T  [NH][NB]
#define OFF_C2   (OFF_C1 + NH*NB)        // c2T  [NH][NB]
#define OFF_PG   (OFF_C2 + NH*NB)        // pgT  [NZ][NB]
#define OFF_CTR  (OFF_PG + NZ*NB)        // barrier counter (unsigned)

__device__ __forceinline__ float sigf(float x) { return 1.f / (1.f + __expf(-x)); }
// tanh via single exp; safe at both tails (exp arg always <= 0)
__device__ __forceinline__ float tanhfast(float x) { return 2.f / (1.f + __expf(-2.f * x)) - 1.f; }

// Monotonic grid barrier: all NWG workgroups are co-resident (256 WGs, 256 thr, 0 LDS).
__device__ __forceinline__ void gbar(unsigned* ctr) {
  __syncthreads();
  if (threadIdx.x == 0) {
    __threadfence();
    unsigned prev = __hip_atomic_fetch_add(ctr, 1u, __ATOMIC_RELEASE, __HIP_MEMORY_SCOPE_AGENT);
    unsigned target = (prev / NWG + 1u) * NWG;
    while (__hip_atomic_load(ctr, __ATOMIC_ACQUIRE, __HIP_MEMORY_SCOPE_AGENT) < target) {
      __builtin_amdgcn_s_sleep(1);
    }
  }
  __syncthreads();
}

__global__ void init_state(const float* __restrict__ h1, const float* __restrict__ c1,
                           const float* __restrict__ h2, const float* __restrict__ c2,
                           const float* __restrict__ pg0, float* __restrict__ ws) {
  int i = blockIdx.x * blockDim.x + threadIdx.x;  // 0..65535 == NH*NB
  int r = i & (NB - 1);
  int u = i >> 6;
  ws[OFF_H1 + u * NB + r] = h1[r * NH + u];   // parity-0 buffer
  ws[OFF_C1 + u * NB + r] = c1[r * NH + u];
  ws[OFF_H2 + u * NB + r] = h2[r * NH + u];
  ws[OFF_C2 + u * NB + r] = c2[r * NH + u];
  if (u < NZ) ws[OFF_PG + u * NB + r] = pg0[r * NZ + u];
  if (i == 0) *(unsigned*)(ws + OFF_CTR) = 0u;
}

// One LSTM phase: thread (r, u) computes all 4 gates (rows u, NH+u, 2NH+u, 3NH+u)
// for hidden unit u, batch row r, then the elementwise update. Gates never hit global.
__device__ __forceinline__ void lstm_phase(
    int u, int r,
    const float* __restrict__ aT0,   // [NH][NB] first K half (x input, col-major)
    const float* __restrict__ aT1,   // [NH][NB] second K half (h_prev, col-major)
    const float* __restrict__ Wih, const float* __restrict__ Whh,
    const float* __restrict__ bih, const float* __restrict__ bhh,
    float* __restrict__ cT, float* __restrict__ hT_out)
{
  float ai = bih[u]          + bhh[u];
  float af = bih[NH + u]     + bhh[NH + u];
  float ag = bih[2 * NH + u] + bhh[2 * NH + u];
  float ao = bih[3 * NH + u] + bhh[3 * NH + u];
  {
    const float* __restrict__ wi = Wih + (size_t)u * NH;
    const float* __restrict__ wf = Wih + (size_t)(NH + u) * NH;
    const float* __restrict__ wg = Wih + (size_t)(2 * NH + u) * NH;
    const float* __restrict__ wo = Wih + (size_t)(3 * NH + u) * NH;
    for (int k = 0; k < NH; ++k) {
      float a = aT0[k * NB + r];
      ai = fmaf(a, wi[k], ai); af = fmaf(a, wf[k], af);
      ag = fmaf(a, wg[k], ag); ao = fmaf(a, wo[k], ao);
    }
  }
  {
    const float* __restrict__ wi = Whh + (size_t)u * NH;
    const float* __restrict__ wf = Whh + (size_t)(NH + u) * NH;
    const float* __restrict__ wg = Whh + (size_t)(2 * NH + u) * NH;
    const float* __restrict__ wo = Whh + (size_t)(3 * NH + u) * NH;
    for (int k = 0; k < NH; ++k) {
      float a = aT1[k * NB + r];
      ai = fmaf(a, wi[k], ai); af = fmaf(a, wf[k], af);
      ag = fmaf(a, wg[k], ag); ao = fmaf(a, wo[k], ao);
    }
  }
  float iv = sigf(ai), fv = sigf(af), gv = tanhfast(ag), ov = sigf(ao);
  float cold = cT[u * NB + r];
  float cn = fmaf(fv, cold, iv * gv);
  cT[u * NB + r] = cn;
  hT_out[u * NB + r] = ov * tanhfast(cn);
}

__global__ __launch_bounds__(NT, 1) void gen_persistent(
    const float* __restrict__ z,
    const float* __restrict__ W1,  const float* __restrict__ b1,
    const float* __restrict__ Wih1, const float* __restrict__ Whh1,
    const float* __restrict__ bih1, const float* __restrict__ bhh1,
    const float* __restrict__ Wih2, const float* __restrict__ Whh2,
    const float* __restrict__ bih2, const float* __restrict__ bhh2,
    const float* __restrict__ W2,  const float* __restrict__ b2,
    float* __restrict__ dout, float* __restrict__ ws)
{
  float* outT = ws + OFF_OUT;
  float* h1T  = ws + OFF_H1;
  float* h2T  = ws + OFF_H2;
  float* c1T  = ws + OFF_C1;
  float* c2T  = ws + OFF_C2;
  float* pgT  = ws + OFF_PG;
  unsigned* ctr = (unsigned*)(ws + OFF_CTR);

  const int w = blockIdx.x;
  const int r = threadIdx.x & 63;
  // wave-uniform lane-group index -> weight-row addresses become scalar loads
  const int xl = __builtin_amdgcn_readfirstlane((int)(threadIdx.x >> 6));
  const int u = 4 * w + xl;   // unit / column owned by this thread (0..1023)

  for (int t = 0; t < NS; ++t) {
    const int par = t & 1;
    // ---- P0: out = relu([z_t, prev_gen] @ W1^T + b1) ----
    {
      const float* __restrict__ wrow = W1 + (size_t)u * (2 * NZ);
      float acc = b1[u];
      const float* __restrict__ zrow = z + ((size_t)r * NS + t) * NZ;
      for (int k = 0; k < NZ; ++k) acc = fmaf(zrow[k], wrow[k], acc);
      for (int k = 0; k < NZ; ++k) acc = fmaf(pgT[k * NB + r], wrow[NZ + k], acc);
      outT[u * NB + r] = fmaxf(acc, 0.f);
    }
    gbar(ctr);
    // ---- P2: LSTM layer 1 (reads outT + h1 parity `par`, writes h1 parity `par^1`) ----
    lstm_phase(u, r, outT, h1T + par * NH * NB, Wih1, Whh1, bih1, bhh1,
               c1T, h1T + (par ^ 1) * NH * NB);
    gbar(ctr);
    // ---- P3: LSTM layer 2 ----
    lstm_phase(u, r, h1T + (par ^ 1) * NH * NB, h2T + par * NH * NB, Wih2, Whh2, bih2, bhh2,
               c2T, h2T + (par ^ 1) * NH * NB);
    gbar(ctr);
    // ---- P4: prev_gen = h2_new @ W2^T + b2; store gen_feats[t] ----
    if (w < NZ / 4) {   // u in 0..255
      const float* __restrict__ wrow = W2 + (size_t)u * NH;
      const float* __restrict__ h2n = h2T + (par ^ 1) * NH * NB;
      float acc = b2[u];
      for (int k = 0; k < NH; ++k) acc = fmaf(h2n[k * NB + r], wrow[k], acc);
      pgT[u * NB + r] = acc;
      dout[((size_t)r * NS + t) * NZ + u] = acc;
    }
    gbar(ctr);
  }

  // Epilogue: final states. Last step t=511 (par=1) wrote parity-0 buffers; each
  // thread reads back exactly the values it wrote itself -> no extra sync needed.
  float* o = dout + (size_t)NB * NS * NZ;
  o[(size_t)r * NH + u]               = h1T[u * NB + r];
  o[(size_t)NB * NH + r * NH + u]     = c1T[u * NB + r];
  o[(size_t)2 * NB * NH + r * NH + u] = h2T[u * NB + r];
  o[(size_t)3 * NB * NH + r * NH + u] = c2T[u * NB + r];
}

extern "C" void kernel_launch(void* const* d_in, const int* in_sizes, int n_in,
                              void* d_out, int out_size, void* d_ws, size_t ws_size,
                              hipStream_t stream) {
  const float* z    = (const float*)d_in[0];
  const float* pg0  = (const float*)d_in[1];
  const float* h1   = (const float*)d_in[2];
  const float* c1   = (const float*)d_in[3];
  const float* h2   = (const float*)d_in[4];
  const float* c2   = (const float*)d_in[5];
  const float* W1   = (const float*)d_in[6];
  const float* b1   = (const float*)d_in[7];
  const float* Wih1 = (const float*)d_in[8];
  const float* Whh1 = (const float*)d_in[9];
  const float* bih1 = (const float*)d_in[10];
  const float* bhh1 = (const float*)d_in[11];
  const float* Wih2 = (const float*)d_in[12];
  const float* Whh2 = (const float*)d_in[13];
  const float* bih2 = (const float*)d_in[14];
  const float* bhh2 = (const float*)d_in[15];
  const float* W2   = (const float*)d_in[16];
  const float* b2   = (const float*)d_in[17];
  float* ws = (float*)d_ws;

  hipLaunchKernelGGL(init_state, dim3(NWG), dim3(NT), 0, stream, h1, c1, h2, c2, pg0, ws);
  hipLaunchKernelGGL(gen_persistent, dim3(NWG), dim3(NT), 0, stream,
                     z, W1, b1, Wih1, Whh1, bih1, bhh1, Wih2, Whh2, bih2, bhh2, W2, b2,
                     (float*)d_out, ws);
}

// Round 2
// 39191.196 us; speedup vs baseline: 7.4316x; 7.4316x over previous
//
#include <hip/hip_runtime.h>

#define NB 64
#define NS 512
#define NZ 256
#define NH 1024
#define NWG 256
#define NT 256

typedef _Float16 f16;
typedef __attribute__((ext_vector_type(8))) _Float16 half8;
typedef __attribute__((ext_vector_type(4))) float f32x4;

// ---------------- ws layout (bytes) ----------------
#define WS_OUTP  0          // f16 [128][64][8]  relu output, packed A-frag layout
#define WS_H1P   131072     // f16 [2][128][64][8]
#define WS_H2P   393216     // f16 [2][128][64][8]
#define WS_C1    655360     // f32 [1024][64]
#define WS_C2    917504     // f32 [1024][64]
#define WS_WF    1179648    // f16 [1024][1024]  Wfused = W1p @ W2
#define WS_B1P   3276800    // f32 [1024]        b1 + W1p@b2
#define WS_PG0   3280896    // f16 [32][64][8]   packed prev_gen0
#define WS_CTR   3313664    // unsigned barrier counter

// ---------------- LDS layout (bytes) ----------------
#define L_W0   0            // 4 rows x 2576  ([W1z 256h | Wfused 1024h] + 16B pad)
#define L_W2   10304        // 1 row  x 2064  (W2[w] 1024h + pad)
#define L_W1   12368        // 16 rows x 4112 ([Wih1 1024h | Whh1 1024h] + pad)
#define L_WP2  78160        // 16 rows x 4112
#define L_W1P  143952       // 4 rows x 528   (W1p 256h + pad) for t==0
#define L_X    146064       // 4 waves x 1024 exchange scratch
#define LDS_BYTES 150160

__device__ __forceinline__ float sigf(float x) { return 1.f / (1.f + __expf(-x)); }
__device__ __forceinline__ float tanhfast(float x) { return 2.f / (1.f + __expf(-2.f * x)) - 1.f; }

__device__ __forceinline__ f32x4 MF(half8 a, half8 b, f32x4 c) {
  return __builtin_amdgcn_mfma_f32_16x16x32_f16(a, b, c, 0, 0, 0);
}

__device__ __forceinline__ void gbar(unsigned* ctr) {
  __syncthreads();
  if (threadIdx.x == 0) {
    __threadfence();
    unsigned prev = __hip_atomic_fetch_add(ctr, 1u, __ATOMIC_RELEASE, __HIP_MEMORY_SCOPE_AGENT);
    unsigned target = (prev / NWG + 1u) * NWG;
    while (__hip_atomic_load(ctr, __ATOMIC_ACQUIRE, __HIP_MEMORY_SCOPE_AGENT) < target) {
      __builtin_amdgcn_s_sleep(1);
    }
  }
  __syncthreads();
}

__global__ void init_state(const float* __restrict__ h1, const float* __restrict__ c1,
                           const float* __restrict__ h2, const float* __restrict__ c2,
                           const float* __restrict__ pg0, const float* __restrict__ W1,
                           const float* __restrict__ b1, const float* __restrict__ b2,
                           char* __restrict__ ws) {
  int i = blockIdx.x * blockDim.x + threadIdx.x;  // 0..65535
  int R = i & 63;
  int U = i >> 6;
  f16* H1p = (f16*)(ws + WS_H1P);
  f16* H2p = (f16*)(ws + WS_H2P);
  float* c1w = (float*)(ws + WS_C1);
  float* c2w = (float*)(ws + WS_C2);
  int pidx = ((U >> 3) * 64 + R) * 8 + (U & 7);
  H1p[pidx] = (f16)h1[(size_t)R * NH + U];
  H2p[pidx] = (f16)h2[(size_t)R * NH + U];
  c1w[U * 64 + R] = c1[(size_t)R * NH + U];
  c2w[U * 64 + R] = c2[(size_t)R * NH + U];
  if (i < 16384) {  // pack prev_gen0: u in 0..255
    int u = i >> 6, r2 = i & 63;
    ((f16*)(ws + WS_PG0))[((u >> 3) * 64 + r2) * 8 + (u & 7)] = (f16)pg0[(size_t)r2 * NZ + u];
  }
  if (i < NH) {  // b1p = b1 + W1p @ b2
    float acc = b1[i];
    const float* wp = W1 + (size_t)i * (2 * NZ) + NZ;
    for (int mm = 0; mm < NZ; ++mm) acc = fmaf(wp[mm], b2[mm], acc);
    ((float*)(ws + WS_B1P))[i] = acc;
  }
  if (i == 0) *(unsigned*)(ws + WS_CTR) = 0u;
}

__global__ void prep_wfused(const float* __restrict__ W1, const float* __restrict__ W2,
                            char* __restrict__ ws) {
  int u = blockIdx.x >> 2;
  int j = ((blockIdx.x & 3) << 8) + threadIdx.x;
  const float* wp = W1 + (size_t)u * (2 * NZ) + NZ;
  float acc = 0.f;
  for (int mm = 0; mm < NZ; ++mm) acc = fmaf(wp[mm], W2[(size_t)mm * NH + j], acc);
  ((f16*)(ws + WS_WF))[(size_t)u * NH + j] = (f16)acc;
}

__global__ __launch_bounds__(NT, 1) void gen_persistent(
    const float* __restrict__ z,
    const float* __restrict__ W1, const float* __restrict__ b1,
    const float* __restrict__ Wih1, const float* __restrict__ Whh1,
    const float* __restrict__ bih1, const float* __restrict__ bhh1,
    const float* __restrict__ Wih2, const float* __restrict__ Whh2,
    const float* __restrict__ bih2, const float* __restrict__ bhh2,
    const float* __restrict__ W2, const float* __restrict__ b2,
    float* __restrict__ dout, char* __restrict__ ws)
{
  extern __shared__ char smem[];
  const int w = blockIdx.x;
  const int tid = threadIdx.x;
  const int m = tid >> 6;      // wave -> batch rows 16m..16m+15
  const int l = tid & 63;
  const int c = l & 15;        // MFMA col / A-row-within-16
  const int kg = l >> 4;       // k-group

  f16* OutP = (f16*)(ws + WS_OUTP);
  f16* H1p = (f16*)(ws + WS_H1P);
  f16* H2p = (f16*)(ws + WS_H2P);
  float* c1w = (float*)(ws + WS_C1);
  float* c2w = (float*)(ws + WS_C2);
  const f16* Wf = (const f16*)(ws + WS_WF);
  const f16* Pg0p = (const f16*)(ws + WS_PG0);
  const float* b1p = (const float*)(ws + WS_B1P);
  unsigned* ctr = (unsigned*)(ws + WS_CTR);

  // ---- load this CU's weight slices into LDS (fp32 -> fp16), once ----
  for (int i = 0; i < 16; ++i) {
    int gi = i >> 2, uu = 4 * w + (i & 3);
    const float* s1i = Wih1 + (size_t)(gi * NH + uu) * NH;
    const float* s1h = Whh1 + (size_t)(gi * NH + uu) * NH;
    const float* s2i = Wih2 + (size_t)(gi * NH + uu) * NH;
    const float* s2h = Whh2 + (size_t)(gi * NH + uu) * NH;
    f16* d1 = (f16*)(smem + L_W1 + i * 4112);
    f16* d2 = (f16*)(smem + L_WP2 + i * 4112);
    for (int k = tid; k < NH; k += NT) {
      d1[k] = (f16)s1i[k]; d1[NH + k] = (f16)s1h[k];
      d2[k] = (f16)s2i[k]; d2[NH + k] = (f16)s2h[k];
    }
  }
  for (int i = 0; i < 4; ++i) {
    int uu = 4 * w + i;
    f16* d0 = (f16*)(smem + L_W0 + i * 2576);
    d0[tid] = (f16)W1[(size_t)uu * (2 * NZ) + tid];           // z part (256 = NT)
    for (int k = tid; k < NH; k += NT) d0[NZ + k] = Wf[(size_t)uu * NH + k];
    f16* dp = (f16*)(smem + L_W1P + i * 528);
    dp[tid] = (f16)W1[(size_t)uu * (2 * NZ) + NZ + tid];      // W1p part for t==0
  }
  {
    f16* dw2 = (f16*)(smem + L_W2);
    for (int k = tid; k < NH; k += NT) dw2[k] = (f16)W2[(size_t)w * NH + k];
  }
  __syncthreads();

  const int R = 16 * m + c;          // batch row (A-frag + epilogue)
  const int U = 4 * w + kg;          // owned unit (epilogue)
  const int hpack = ((U >> 3) * 64 + R) * 8 + (U & 7);
  const float b0fused = b1p[U];
  const float b0plain = b1[U];
  const float bi1 = bih1[U] + bhh1[U];
  const float bf1 = bih1[NH + U] + bhh1[NH + U];
  const float bg1 = bih1[2 * NH + U] + bhh1[2 * NH + U];
  const float bo1 = bih1[3 * NH + U] + bhh1[3 * NH + U];
  const float bi2 = bih2[U] + bhh2[U];
  const float bf2 = bih2[NH + U] + bhh2[NH + U];
  const float bg2 = bih2[2 * NH + U] + bhh2[2 * NH + U];
  const float bo2 = bih2[3 * NH + U] + bhh2[3 * NH + U];
  const float b2w = b2[w];

  float* scr = (float*)(smem + L_X) + m * 256;
  const char* brow0 = smem + L_W0 + (c & 3) * 2576 + kg * 16;
  const char* brow2 = smem + L_W2 + kg * 16;
  const char* brow1 = smem + L_W1 + c * 4112 + kg * 16;
  const char* browp2 = smem + L_WP2 + c * 4112 + kg * 16;
  const char* browp0 = smem + L_W1P + (c & 3) * 528 + kg * 16;
  const float* zlane = z + (size_t)R * NS * NZ + kg * 8;

  for (int t = 0; t < NS; ++t) {
    const int par = t & 1;
    const f16* h2prev = H2p + par * 65536;
    const f16* h1prev = H1p + par * 65536;

    // ---------- P0: out = relu(z@W1z^T + h2prev@Wfused^T + b) ; lazy pg(t-1) ----------
    f32x4 ao0 = {0.f, 0.f, 0.f, 0.f}, ao1 = ao0, ap0 = ao0, ap1 = ao0;
    {
      const float* zt = zlane + (size_t)t * NZ;
      #pragma unroll
      for (int kk = 0; kk < 8; ++kk) {
        f32x4 f0 = *(const f32x4*)(zt + kk * 32);
        f32x4 f1 = *(const f32x4*)(zt + kk * 32 + 4);
        half8 a;
        a[0] = (f16)f0[0]; a[1] = (f16)f0[1]; a[2] = (f16)f0[2]; a[3] = (f16)f0[3];
        a[4] = (f16)f1[0]; a[5] = (f16)f1[1]; a[6] = (f16)f1[2]; a[7] = (f16)f1[3];
        half8 b = *(const half8*)(brow0 + kk * 64);
        if (kk & 1) ao1 = MF(a, b, ao1); else ao0 = MF(a, b, ao0);
      }
      if (t == 0) {  // true prev_gen0 path through W1p
        #pragma unroll
        for (int kk = 0; kk < 8; ++kk) {
          half8 a = *(const half8*)(Pg0p + (((4 * kk + kg) * 64 + R) << 3));
          half8 b = *(const half8*)(browp0 + kk * 64);
          if (kk & 1) ao1 = MF(a, b, ao1); else ao0 = MF(a, b, ao0);
        }
      } else {       // fused h2 path; A-frags shared with lazy pg
        #pragma unroll 4
        for (int kk = 0; kk < 32; ++kk) {
          half8 a = *(const half8*)(h2prev + (((4 * kk + kg) * 64 + R) << 3));
          half8 bwf = *(const half8*)(brow0 + 512 + kk * 64);
          half8 bw2 = *(const half8*)(brow2 + kk * 64);
          if (kk & 1) { ao1 = MF(a, bwf, ao1); ap1 = MF(a, bw2, ap1); }
          else        { ao0 = MF(a, bwf, ao0); ap0 = MF(a, bw2, ap0); }
        }
      }
    }
    {
      f32x4 D = ao0 + ao1;
      if (c < 4) {
        #pragma unroll
        for (int v = 0; v < 4; ++v) scr[c * 16 + kg * 4 + v] = D[v];
      }
      float pre = scr[kg * 16 + c] + ((t == 0) ? b0plain : b0fused);
      OutP[hpack] = (f16)fmaxf(pre, 0.f);
      if (t > 0 && c == 0) {
        f32x4 Dp = ap0 + ap1;
        #pragma unroll
        for (int v = 0; v < 4; ++v) {
          int Rp = 16 * m + kg * 4 + v;
          dout[((size_t)Rp * NS + (t - 1)) * NZ + w] = Dp[v] + b2w;
        }
      }
    }
    gbar(ctr);

    // ---------- P1: LSTM layer 1 ----------
    {
      f32x4 g0 = {0.f, 0.f, 0.f, 0.f}, g1 = g0;
      #pragma unroll 4
      for (int kk = 0; kk < 32; ++kk) {
        half8 a = *(const half8*)(OutP + (((4 * kk + kg) * 64 + R) << 3));
        half8 b = *(const half8*)(brow1 + kk * 64);
        if (kk & 1) g1 = MF(a, b, g1); else g0 = MF(a, b, g0);
      }
      #pragma unroll 4
      for (int kk = 0; kk < 32; ++kk) {
        half8 a = *(const half8*)(h1prev + (((4 * kk + kg) * 64 + R) << 3));
        half8 b = *(const half8*)(brow1 + 2048 + kk * 64);
        if (kk & 1) g1 = MF(a, b, g1); else g0 = MF(a, b, g0);
      }
      f32x4 D = g0 + g1;
      #pragma unroll
      for (int v = 0; v < 4; ++v) scr[c * 16 + kg * 4 + v] = D[v];
      float ai = scr[kg * 16 + c];
      float af = scr[(4 + kg) * 16 + c];
      float ag = scr[(8 + kg) * 16 + c];
      float aoo = scr[(12 + kg) * 16 + c];
      float iv = sigf(ai + bi1), fv = sigf(af + bf1);
      float gv = tanhfast(ag + bg1), ov = sigf(aoo + bo1);
      float cold = c1w[U * 64 + R];
      float cn = fmaf(fv, cold, iv * gv);
      c1w[U * 64 + R] = cn;
      H1p[(par ^ 1) * 65536 + hpack] = (f16)(ov * tanhfast(cn));
    }
    gbar(ctr);

    // ---------- P2: LSTM layer 2 ----------
    {
      const f16* h1new = H1p + (par ^ 1) * 65536;
      f32x4 q0 = {0.f, 0.f, 0.f, 0.f}, q1 = q0;
      #pragma unroll 4
      for (int kk = 0; kk < 32; ++kk) {
        half8 a = *(const half8*)(h1new + (((4 * kk + kg) * 64 + R) << 3));
        half8 b = *(const half8*)(browp2 + kk * 64);
        if (kk & 1) q1 = MF(a, b, q1); else q0 = MF(a, b, q0);
      }
      #pragma unroll 4
      for (int kk = 0; kk < 32; ++kk) {
        half8 a = *(const half8*)(h2prev + (((4 * kk + kg) * 64 + R) << 3));
        half8 b = *(const half8*)(browp2 + 2048 + kk * 64);
        if (kk & 1) q1 = MF(a, b, q1); else q0 = MF(a, b, q0);
      }
      f32x4 D = q0 + q1;
      #pragma unroll
      for (int v = 0; v < 4; ++v) scr[c * 16 + kg * 4 + v] = D[v];
      float ai = scr[kg * 16 + c];
      float af = scr[(4 + kg) * 16 + c];
      float ag = scr[(8 + kg) * 16 + c];
      float aoo = scr[(12 + kg) * 16 + c];
      float iv = sigf(ai + bi2), fv = sigf(af + bf2);
      float gv = tanhfast(ag + bg2), ov = sigf(aoo + bo2);
      float cold = c2w[U * 64 + R];
      float cn = fmaf(fv, cold, iv * gv);
      c2w[U * 64 + R] = cn;
      H2p[(par ^ 1) * 65536 + hpack] = (f16)(ov * tanhfast(cn));
    }
    gbar(ctr);
  }

  // ---------- tail: pg for t=511 from final h2 (parity 0) ----------
  {
    f32x4 ap0 = {0.f, 0.f, 0.f, 0.f}, ap1 = ap0;
    #pragma unroll 4
    for (int kk = 0; kk < 32; ++kk) {
      half8 a = *(const half8*)(H2p + (((4 * kk + kg) * 64 + R) << 3));
      half8 b = *(const half8*)(brow2 + kk * 64);
      if (kk & 1) ap1 = MF(a, b, ap1); else ap0 = MF(a, b, ap0);
    }
    if (c == 0) {
      f32x4 Dp = ap0 + ap1;
      #pragma unroll
      for (int v = 0; v < 4; ++v) {
        int Rp = 16 * m + kg * 4 + v;
        dout[((size_t)Rp * NS + (NS - 1)) * NZ + w] = Dp[v] + b2w;
      }
    }
  }

  // ---------- final states ----------
  {
    int U3 = 4 * w + (tid >> 6);
    int R3 = tid & 63;
    int hp3 = ((U3 >> 3) * 64 + R3) * 8 + (U3 & 7);
    float* o = dout + (size_t)NB * NS * NZ;
    o[(size_t)R3 * NH + U3] = (float)H1p[hp3];                          // h1 (parity 0)
    o[(size_t)NB * NH + (size_t)R3 * NH + U3] = c1w[U3 * 64 + R3];      // c1
    o[2 * (size_t)NB * NH + (size_t)R3 * NH + U3] = (float)H2p[hp3];    // h2 (parity 0)
    o[3 * (size_t)NB * NH + (size_t)R3 * NH + U3] = c2w[U3 * 64 + R3];  // c2
  }
}

extern "C" void kernel_launch(void* const* d_in, const int* in_sizes, int n_in,
                              void* d_out, int out_size, void* d_ws, size_t ws_size,
                              hipStream_t stream) {
  const float* z    = (const float*)d_in[0];
  const float* pg0  = (const float*)d_in[1];
  const float* h1   = (const float*)d_in[2];
  const float* c1   = (const float*)d_in[3];
  const float* h2   = (const float*)d_in[4];
  const float* c2   = (const float*)d_in[5];
  const float* W1   = (const float*)d_in[6];
  const float* b1   = (const float*)d_in[7];
  const float* Wih1 = (const float*)d_in[8];
  const float* Whh1 = (const float*)d_in[9];
  const float* bih1 = (const float*)d_in[10];
  const float* bhh1 = (const float*)d_in[11];
  const float* Wih2 = (const float*)d_in[12];
  const float* Whh2 = (const float*)d_in[13];
  const float* bih2 = (const float*)d_in[14];
  const float* bhh2 = (const float*)d_in[15];
  const float* W2   = (const float*)d_in[16];
  const float* b2   = (const float*)d_in[17];
  char* ws = (char*)d_ws;
  float* out = (float*)d_out;

  hipLaunchKernelGGL(init_state, dim3(256), dim3(256), 0, stream,
                     h1, c1, h2, c2, pg0, W1, b1, b2, ws);
  hipLaunchKernelGGL(prep_wfused, dim3(4096), dim3(256), 0, stream, W1, W2, ws);
  hipLaunchKernelGGL(gen_persistent, dim3(NWG), dim3(NT), LDS_BYTES, stream,
                     z, W1, b1, Wih1, Whh1, bih1, bhh1, Wih2, Whh2, bih2, bhh2, W2, b2,
                     out, ws);
}